// Round 4
// baseline (342.560 us; speedup 1.0000x reference)
//
#include <hip/hip_runtime.h>
#include <hip/hip_bf16.h>
#include <stdint.h>

// TernaryConv2d: y = conv2d(x, alpha*ternary(W), SAME) + b
// x: (32,56,56,256) NHWC fp32, W: (3,3,256,256) HWIO fp32, b: (256,) fp32
// Implicit GEMM: M=100352, N=256, K=2304. bf16 MFMA, alpha fp32 epilogue.
//
// R1: reduction atomics fixed (670->349).
// R2: XOR-swizzled LDS chunks, kc-outer/tap-inner K-loop, fused sumabs (349->299).
// R3: 256x256/8-phase port REGRESSED (conv 123->153): 392 blocks @ 1 blk/CU =
//     76.6% packing tail. REVERTED.
// R4/R5: memset+atomics removed, 3 dispatches: only -5us (294). => the ~170us
//     non-conv residue is NOT dispatch overhead; it's pad-kernel time and/or
//     ws-proportional harness restore (ws was 56.3MB, mostly xpad).
// R6: xpad ELIMINATED. conv stages A directly from fp32 x with per-row halo
//     predication, converts in registers (same RNE f2bf), ds_write_b128 into
//     the identical swizzled LDS slots. B stays global_load_lds. ws 56MB->1.2MB.
//     Numerically bitwise-identical to R5 (same operands, same MFMA order).
//
// ws layout:
//   [0..2303]   : pr[288] double  — per-block sum|W| partials
//   [2560..4863]: qv[288] double  — per-block sum|W beyond t| partials
//   [5120..7423]: qc[288] ull     — per-block count-beyond partials
//   [8192..]    : WqT bf16 [256 co][2304 k]  (k = tap*256 + ci), 1.18MB

typedef __attribute__((ext_vector_type(8))) short short8;
typedef __attribute__((ext_vector_type(4))) float floatx4;

#define NW_ELEMS 589824        // 3*3*256*256
#define K_TOTAL 2304
#define PR_OFF 0
#define QV_OFF 2560
#define QC_OFF 5120
#define WQT_OFF 8192
#define RED_BLOCKS 288         // 288*256*8 == NW_ELEMS exactly

__device__ __forceinline__ void async16(const void* g, void* l) {
  __builtin_amdgcn_global_load_lds(
      (const __attribute__((address_space(1))) void*)g,
      (__attribute__((address_space(3))) void*)l, 16, 0, 0);
}

__device__ __forceinline__ ushort f2bf(float f) {
  __hip_bfloat16 h = __float2bfloat16(f);
  return *reinterpret_cast<ushort*>(&h);
}

// ---- sum|W| -> pr[bid] (288 blocks) ----
__global__ __launch_bounds__(256) void sumabs_kernel(
    const float* __restrict__ W, double* __restrict__ pr) {
  __shared__ double sds[4];
  double v = 0.0;
#pragma unroll
  for (int j = 0; j < 8; j++) {
    uint i = (blockIdx.x * 8 + j) * 256 + threadIdx.x;
    v += (double)fabsf(W[i]);
  }
#pragma unroll
  for (int off = 32; off; off >>= 1) v += __shfl_down(v, off);
  if ((threadIdx.x & 63) == 0) sds[threadIdx.x >> 6] = v;
  __syncthreads();
  if (threadIdx.x == 0) pr[blockIdx.x] = sds[0] + sds[1] + sds[2] + sds[3];
}

// ---- ternarize: WqT[co][k] in {-1,0,+1}; per-block alpha-stat partials ----
__global__ __launch_bounds__(256) void quant_kernel(
    const float* __restrict__ W, ushort* __restrict__ WqT,
    const double* __restrict__ pr, double* __restrict__ qv,
    unsigned long long* __restrict__ qc) {
  __shared__ double sds[4];
  __shared__ unsigned long long cds[4];
  // global sum|W| from the 288 partials (L2-hot, plain loads, no atomics)
  double p = pr[threadIdx.x];
  if (threadIdx.x < 32) p += pr[256 + threadIdx.x];
#pragma unroll
  for (int off = 32; off; off >>= 1) p += __shfl_down(p, off);
  if ((threadIdx.x & 63) == 0) sds[threadIdx.x >> 6] = p;
  __syncthreads();
  double s = sds[0] + sds[1] + sds[2] + sds[3];
  float t = (float)(0.7 * (s / (double)NW_ELEMS));
  __syncthreads();  // sds reused below

  double v = 0.0;
  unsigned long long cnt = 0;
  ushort u[8];
#pragma unroll
  for (int j = 0; j < 8; j++) {
    uint i = (blockIdx.x * 8 + j) * 256 + threadIdx.x;
    float w = W[i];
    bool pos = (w > t), neg = (w < -t);
    u[j] = pos ? (ushort)0x3F80 : (neg ? (ushort)0xBF80 : (ushort)0);
    if (pos || neg) { v += (double)fabsf(w); cnt++; }
  }
  // thread (bid,tid) owns WqT[co=tid][k = bid*8 .. bid*8+7]: one 16B store
  *(uint4*)(WqT + (size_t)threadIdx.x * K_TOTAL + blockIdx.x * 8) = *(uint4*)u;
#pragma unroll
  for (int off = 32; off; off >>= 1) {
    v += __shfl_down(v, off);
    cnt += __shfl_down(cnt, off);
  }
  if ((threadIdx.x & 63) == 0) { sds[threadIdx.x >> 6] = v; cds[threadIdx.x >> 6] = cnt; }
  __syncthreads();
  if (threadIdx.x == 0) {
    qv[blockIdx.x] = sds[0] + sds[1] + sds[2] + sds[3];
    qc[blockIdx.x] = cds[0] + cds[1] + cds[2] + cds[3];
  }
}

// ---- implicit-GEMM conv: 128x128 tile, BK=64, 16x16x32 bf16 MFMA ----
// A staged from fp32 x DIRECTLY (reg-staged: predicated loads + f2bf +
// ds_write_b128); halo taps produce zeros via predication. B via
// global_load_lds of WqT (bf16). LDS layout identical to R2/R5: slot for
// (row, chunk) holds global chunk chunk^(row&7); readers fetch slot
// (kk*4+fq)^(fr&7) -> conflict-free (verified: 0).
__global__ __launch_bounds__(256, 2) void conv_kernel(
    const float* __restrict__ x, const ushort* __restrict__ WqT,
    const double* __restrict__ qv, const unsigned long long* __restrict__ qc,
    const float* __restrict__ bias, float* __restrict__ out) {
  __shared__ __attribute__((aligned(16))) ushort Alds[128 * 64];  // 16 KB
  __shared__ __attribute__((aligned(16))) ushort Blds[128 * 64];  // 16 KB
  __shared__ double ads[4];
  __shared__ double acs[4];
  uint tid = threadIdx.x;
  uint bm = blockIdx.x >> 1, bn = blockIdx.x & 1;

  // staging map: thread (rbase,chunk) handles global chunk ceff = chunk^(r&7)
  uint chunk = tid & 7;
  uint rbase = tid >> 3;       // 0..31
  uint ceff = chunk ^ (rbase & 7);
  int hh[4], ww[4];
  int abase[4];                // element offset of (n, h-1, w-1) + ceff*8
  const ushort* bsrc[4];
#pragma unroll
  for (int i = 0; i < 4; i++) {
    uint row = i * 32 + rbase;
    uint gm = bm * 128 + row;
    uint n = gm / 3136;
    uint rem = gm - n * 3136;
    uint h = rem / 56;
    uint w = rem - h * 56;
    hh[i] = (int)h;
    ww[i] = (int)w;
    abase[i] = (((int)n * 56 + (int)h - 1) * 56 + (int)w - 1) * 256 + (int)(ceff * 8);
    bsrc[i] = WqT + ((size_t)(bn * 128 + row) * K_TOTAL + ceff * 8);
  }

  floatx4 acc[4][4];
#pragma unroll
  for (int mt = 0; mt < 4; mt++)
#pragma unroll
    for (int nt = 0; nt < 4; nt++) acc[mt][nt] = (floatx4){0.f, 0.f, 0.f, 0.f};

  uint lane = tid & 63;
  uint wv = tid >> 6;
  uint wm = wv >> 1, wn = wv & 1;   // 2x2 wave grid, each 64x64
  uint fr = lane & 15, fq = lane >> 4;
  uint a_row = (wm * 64 + fr) * 128;  // + mt*2048 + swz-chunk*16 (bytes)
  uint b_row = (wn * 64 + fr) * 128;
  uint swz = (fr & 7) * 16;           // XOR byte offset applied to chunk slot

  // K-loop: kc-outer, tap-inner (taps 1 step apart -> A re-reads L2-hot)
  for (int ks = 0; ks < 36; ks++) {
    uint kcq = (uint)ks / 9;
    uint tap = (uint)ks - kcq * 9;
    int ky = (int)(tap / 3);
    int kx = (int)(tap - ky * 3);
    int aoffe = (ky * 56 + kx) * 256 + (int)(kcq * 64);  // elements into x
    uint boffe = tap * 256 + kcq * 64;                   // along WqT row

    __syncthreads();  // previous tile fully consumed by all waves
    // B: async direct-to-LDS (fire and forget; drained at next barrier)
#pragma unroll
    for (int i = 0; i < 4; i++)
      async16(bsrc[i] + boffe, (char*)Blds + i * 4096 + tid * 16);
    // A: reg-staged fp32 -> bf16 -> LDS (halo -> zeros via predication)
#pragma unroll
    for (int i = 0; i < 4; i++) {
      int ih = hh[i] + ky - 1;
      int iw = ww[i] + kx - 1;
      bool valid = ((uint)ih < 56u) && ((uint)iw < 56u);
      float4 f0 = {0.f, 0.f, 0.f, 0.f}, f1 = {0.f, 0.f, 0.f, 0.f};
      if (valid) {
        const float* p = x + (abase[i] + aoffe);
        f0 = *(const float4*)p;
        f1 = *(const float4*)(p + 4);
      }
      ushort u[8];
      u[0] = f2bf(f0.x); u[1] = f2bf(f0.y); u[2] = f2bf(f0.z); u[3] = f2bf(f0.w);
      u[4] = f2bf(f1.x); u[5] = f2bf(f1.y); u[6] = f2bf(f1.z); u[7] = f2bf(f1.w);
      *(uint4*)((char*)Alds + i * 4096 + tid * 16) = *(uint4*)u;
    }
    __syncthreads();  // drains vmcnt (B async) + lgkmcnt (A writes)

#pragma unroll
    for (int kk = 0; kk < 2; kk++) {
      uint csl = ((uint)(kk * 64) + fq * 16) ^ swz;  // swizzled chunk slot
      short8 af[4], bfr[4];
#pragma unroll
      for (int mt = 0; mt < 4; mt++)
        af[mt] = *(const short8*)((const char*)Alds + a_row + mt * 2048 + csl);
#pragma unroll
      for (int nt = 0; nt < 4; nt++)
        bfr[nt] = *(const short8*)((const char*)Blds + b_row + nt * 2048 + csl);
#pragma unroll
      for (int mt = 0; mt < 4; mt++)
#pragma unroll
        for (int nt = 0; nt < 4; nt++)
          acc[mt][nt] = __builtin_amdgcn_mfma_f32_16x16x32_bf16(
              af[mt], bfr[nt], acc[mt][nt], 0, 0, 0);
    }
  }

  // alpha = sum(qv)/sum(qc) from 288 partials (L2-hot; block-redundant)
  double av = qv[tid];
  double ac = (double)qc[tid];
  if (tid < 32) { av += qv[256 + tid]; ac += (double)qc[256 + tid]; }
#pragma unroll
  for (int off = 32; off; off >>= 1) {
    av += __shfl_down(av, off);
    ac += __shfl_down(ac, off);
  }
  if ((tid & 63) == 0) { ads[tid >> 6] = av; acs[tid >> 6] = ac; }
  __syncthreads();
  float alpha = (float)((ads[0] + ads[1] + ads[2] + ads[3]) /
                        (acs[0] + acs[1] + acs[2] + acs[3]));

  // epilogue: alpha * acc + bias, fp32 store
  // C/D layout (m89/m91): col = lane&15, row = (lane>>4)*4 + reg
#pragma unroll
  for (int mt = 0; mt < 4; mt++) {
    uint mb = bm * 128 + wm * 64 + mt * 16 + fq * 4;
#pragma unroll
    for (int r = 0; r < 4; r++) {
      float* orow = out + (size_t)(mb + r) * 256;
#pragma unroll
      for (int nt = 0; nt < 4; nt++) {
        uint n = bn * 128 + wn * 64 + nt * 16 + fr;
        orow[n] = acc[mt][nt][r] * alpha + bias[n];
      }
    }
  }
}

extern "C" void kernel_launch(void* const* d_in, const int* in_sizes, int n_in,
                              void* d_out, int out_size, void* d_ws, size_t ws_size,
                              hipStream_t stream) {
  const float* x = (const float*)d_in[0];
  const float* W = (const float*)d_in[1];
  const float* b = (const float*)d_in[2];
  float* out = (float*)d_out;

  double* pr = (double*)((char*)d_ws + PR_OFF);
  double* qv = (double*)((char*)d_ws + QV_OFF);
  unsigned long long* qc = (unsigned long long*)((char*)d_ws + QC_OFF);
  ushort* WqT = (ushort*)((char*)d_ws + WQT_OFF);

  sumabs_kernel<<<RED_BLOCKS, 256, 0, stream>>>(W, pr);
  quant_kernel<<<RED_BLOCKS, 256, 0, stream>>>(W, WqT, pr, qv, qc);
  conv_kernel<<<1568, 256, 0, stream>>>(x, WqT, qv, qc, b, out);
}